// Round 1
// baseline (358.781 us; speedup 1.0000x reference)
//
#include <hip/hip_runtime.h>
#include <cstdint>
#include <cstddef>

// ---------------------------------------------------------------------------
// QuaternionPhasorBlock: K/V projections (fp16 MFMA GEMM), quaternion bind,
// segmented cumsum over L, retrieval, LayerNorm, output GEMM w/ residual.
// Workspace requirement: ~210 MB.
// ---------------------------------------------------------------------------

typedef float    f32x4 __attribute__((ext_vector_type(4)));
typedef _Float16 f16x8 __attribute__((ext_vector_type(8)));
typedef _Float16 f16x4 __attribute__((ext_vector_type(4)));

#define DEV static __device__ __forceinline__

constexpr int BATCH = 4;
constexpr int LSEQ  = 4096;
constexpr int DIMN  = 1024;
constexpr int MROW  = BATCH * LSEQ;   // 16384 rows
constexpr int SEG   = 64;             // segments along L
constexpr int SL    = LSEQ / SEG;     // 64 steps per segment

DEV f32x4 qmul(f32x4 a, f32x4 b) {
  f32x4 r;
  r.x = a.x*b.x - a.y*b.y - a.z*b.z - a.w*b.w;
  r.y = a.x*b.y + a.y*b.x + a.z*b.w - a.w*b.z;
  r.z = a.x*b.z - a.y*b.w + a.z*b.x + a.w*b.y;
  r.w = a.x*b.w + a.y*b.z - a.z*b.y + a.w*b.x;
  return r;
}

// ---------------- fp32 -> fp16 cast (vectorized) ----------------
__global__ __launch_bounds__(256) void k_cast_f16(const float* __restrict__ in,
                                                  _Float16* __restrict__ out, int n4) {
  int i = blockIdx.x * 256 + threadIdx.x;
  if (i < n4) {
    f32x4 v = ((const f32x4*)in)[i];
    f16x4 o = { (_Float16)v.x, (_Float16)v.y, (_Float16)v.z, (_Float16)v.w };
    ((f16x4*)out)[i] = o;
  }
}

// ---------------- GEMM: C[M][N] = A[M][K] @ Bw[N][K]^T (+bias, +resid) -----
// 128x128 tile, BK=64, 4 waves (2x2 of 64x64), mfma_f32_16x16x32_f16.
// LDS XOR swizzle (16B slot ^= row&7) applied via pre-swizzled global source
// (global_load_lds writes linearly: wave-uniform base + lane*16).
__global__ __launch_bounds__(256) void k_gemm(const _Float16* __restrict__ A,
                                              const _Float16* __restrict__ Bw,
                                              const float* __restrict__ bias,
                                              const float* __restrict__ resid,
                                              float* __restrict__ C) {
  constexpr int BK = 64;
  __shared__ alignas(16) _Float16 sA[128 * BK];
  __shared__ alignas(16) _Float16 sB[128 * BK];
  const int tid  = threadIdx.x;
  const int lane = tid & 63;
  const int wid  = tid >> 6;
  const int bn = blockIdx.x & 7;        // N/128 = 8
  const int bm = blockIdx.x >> 3;       // M/128 = 128
  const int wr = wid >> 1, wc = wid & 1;

  f32x4 acc[4][4];
#pragma unroll
  for (int m = 0; m < 4; ++m)
#pragma unroll
    for (int n = 0; n < 4; ++n) acc[m][n] = (f32x4){0.f, 0.f, 0.f, 0.f};

  const int rIn  = lane >> 3;                 // row within 8-row chunk
  const int slot = (lane & 7) ^ rIn;          // pre-swizzled source 16B slot
  const char* aBase = (const char*)(A + (size_t)bm * 128 * DIMN);
  const char* bBase = (const char*)(Bw + (size_t)bn * 128 * DIMN);

  for (int ks = 0; ks < DIMN / BK; ++ks) {
    __syncthreads();
    const int kByte = ks * BK * 2;
#pragma unroll
    for (int i = 0; i < 4; ++i) {
      const int c = wid * 4 + i;              // 1KB chunk id (16 per tile)
      const size_t off = (size_t)(c * 8 + rIn) * (DIMN * 2) + kByte + (slot << 4);
      __builtin_amdgcn_global_load_lds(
          (__attribute__((address_space(1))) void*)(aBase + off),
          (__attribute__((address_space(3))) void*)((char*)sA + c * 1024), 16, 0, 0);
      __builtin_amdgcn_global_load_lds(
          (__attribute__((address_space(1))) void*)(bBase + off),
          (__attribute__((address_space(3))) void*)((char*)sB + c * 1024), 16, 0, 0);
    }
    __syncthreads();
#pragma unroll
    for (int kk = 0; kk < 2; ++kk) {
      f16x8 af[4], bf[4];
#pragma unroll
      for (int m = 0; m < 4; ++m) {
        const int row = wr * 64 + m * 16 + (lane & 15);
        const int ls  = (lane >> 4) + kk * 4;
        af[m] = *(const f16x8*)((const char*)sA + row * 128 + (((ls ^ row) & 7) << 4));
      }
#pragma unroll
      for (int n = 0; n < 4; ++n) {
        const int row = wc * 64 + n * 16 + (lane & 15);
        const int ls  = (lane >> 4) + kk * 4;
        bf[n] = *(const f16x8*)((const char*)sB + row * 128 + (((ls ^ row) & 7) << 4));
      }
#pragma unroll
      for (int m = 0; m < 4; ++m)
#pragma unroll
        for (int n = 0; n < 4; ++n)
          acc[m][n] = __builtin_amdgcn_mfma_f32_16x16x32_f16(af[m], bf[n], acc[m][n], 0, 0, 0);
    }
  }

  // Epilogue: C/D frag layout col=lane&15, row=(lane>>4)*4+reg (m89-verified)
  const int rowBase = bm * 128 + wr * 64 + (lane >> 4) * 4;
  const int colBase = bn * 128 + wc * 64 + (lane & 15);
#pragma unroll
  for (int n = 0; n < 4; ++n) {
    const int col = colBase + n * 16;
    const float bc = bias[col];
#pragma unroll
    for (int m = 0; m < 4; ++m) {
#pragma unroll
      for (int t = 0; t < 4; ++t) {
        const int row = rowBase + m * 16 + t;
        const size_t off = (size_t)row * DIMN + col;
        float v = acc[m][n][t] + bc;
        if (resid) v += resid[off];
        C[off] = v;
      }
    }
  }
}

// ---------------- normalize keys, bind = qmul(v, khat), per-segment sums ---
// In-place: Kb -> khat, Vb -> bound. One block per (b, seg), thread = quat n.
__global__ __launch_bounds__(256) void k_bound_segsum(float* __restrict__ Kb,
                                                      float* __restrict__ Vb,
                                                      float* __restrict__ segsum) {
  const int b = blockIdx.x >> 6;     // SEG=64
  const int seg = blockIdx.x & 63;
  const int n = threadIdx.x;
  f32x4 ssum = (f32x4){0.f, 0.f, 0.f, 0.f};
  size_t base = ((size_t)(b * LSEQ + seg * SL)) * 256 + n;
  for (int l = 0; l < SL; ++l) {
    const size_t qi = base + (size_t)l * 256;
    f32x4 kq = ((const f32x4*)Kb)[qi];
    f32x4 vq = ((const f32x4*)Vb)[qi];
    float nn = sqrtf(kq.x*kq.x + kq.y*kq.y + kq.z*kq.z + kq.w*kq.w);
    float s  = 1.0f / fmaxf(nn, 1e-12f);
    f32x4 kh = kq * s;
    f32x4 bd = qmul(vq, kh);
    ((f32x4*)Kb)[qi] = kh;
    ((f32x4*)Vb)[qi] = bd;
    ssum += bd;
  }
  ((f32x4*)segsum)[(size_t)blockIdx.x * 256 + n] = ssum;
}

// ---------------- exclusive scan of segment sums (per scalar channel) ------
__global__ __launch_bounds__(256) void k_segscan(const float* __restrict__ segsum,
                                                 float* __restrict__ segoff) {
  const int gt = blockIdx.x * 256 + threadIdx.x;  // 0..4095
  const int b = gt >> 10, ch = gt & 1023;
  float run = 0.f;
  for (int s = 0; s < SEG; ++s) {
    const size_t idx = ((size_t)(b * SEG + s)) * 1024 + ch;
    float v = segsum[idx];
    segoff[idx] = run;
    run += v;
  }
}

// ---------------- scan within segment + retrieve (in place over bound) -----
__global__ __launch_bounds__(256) void k_retrieve(const float* __restrict__ Kh,
                                                  float* __restrict__ Vb,
                                                  const float* __restrict__ segoff) {
  const int b = blockIdx.x >> 6;
  const int seg = blockIdx.x & 63;
  const int n = threadIdx.x;
  f32x4 mem = ((const f32x4*)segoff)[(size_t)blockIdx.x * 256 + n];
  size_t base = ((size_t)(b * LSEQ + seg * SL)) * 256 + n;
  for (int l = 0; l < SL; ++l) {
    const size_t qi = base + (size_t)l * 256;
    f32x4 bd = ((const f32x4*)Vb)[qi];
    f32x4 kh = ((const f32x4*)Kh)[qi];
    mem += bd;
    f32x4 kc = (f32x4){kh.x, -kh.y, -kh.z, -kh.w};
    f32x4 r = qmul(mem, kc);
    const int gl = seg * SL + l;
    r *= rsqrtf((float)(gl + 1));   // /sqrt(position); LN-invariant anyway
    ((f32x4*)Vb)[qi] = r;
  }
}

// ---------------- LayerNorm over D=1024, emit fp16 for output GEMM ---------
__global__ __launch_bounds__(256) void k_ln(const float* __restrict__ R,
                                            const float* __restrict__ g,
                                            const float* __restrict__ bb,
                                            _Float16* __restrict__ out) {
  const int row = blockIdx.x, t = threadIdx.x;
  f32x4 v = ((const f32x4*)R)[(size_t)row * 256 + t];
  float s1 = v.x + v.y + v.z + v.w;
  float s2 = v.x*v.x + v.y*v.y + v.z*v.z + v.w*v.w;
#pragma unroll
  for (int off = 32; off > 0; off >>= 1) {
    s1 += __shfl_down(s1, off, 64);
    s2 += __shfl_down(s2, off, 64);
  }
  __shared__ float p1[4], p2[4];
  const int wid = t >> 6, lane = t & 63;
  if (lane == 0) { p1[wid] = s1; p2[wid] = s2; }
  __syncthreads();
  const float ts1 = p1[0] + p1[1] + p1[2] + p1[3];
  const float ts2 = p2[0] + p2[1] + p2[2] + p2[3];
  const float mu = ts1 * (1.0f / 1024.0f);
  const float var = ts2 * (1.0f / 1024.0f) - mu * mu;
  const float rstd = rsqrtf(var + 1e-5f);
  f32x4 gg = ((const f32x4*)g)[t];
  f32x4 bv = ((const f32x4*)bb)[t];
  f32x4 nv = (v - mu) * rstd * gg + bv;
  f16x4 o = { (_Float16)nv.x, (_Float16)nv.y, (_Float16)nv.z, (_Float16)nv.w };
  ((f16x4*)out)[(size_t)row * 256 + t] = o;
}

// ---------------------------------------------------------------------------
extern "C" void kernel_launch(void* const* d_in, const int* in_sizes, int n_in,
                              void* d_out, int out_size, void* d_ws, size_t ws_size,
                              hipStream_t stream) {
  const float* x    = (const float*)d_in[0];
  const float* Wk   = (const float*)d_in[1];
  const float* bk   = (const float*)d_in[2];
  const float* Wv   = (const float*)d_in[3];
  const float* bv   = (const float*)d_in[4];
  const float* ln_g = (const float*)d_in[5];
  const float* ln_b = (const float*)d_in[6];
  const float* Wo   = (const float*)d_in[7];
  const float* bo   = (const float*)d_in[8];
  float* out = (float*)d_out;

  char* ws = (char*)d_ws;
  size_t off = 0;
  auto alloc = [&](size_t bytes) -> void* {
    void* p = ws + off;
    off += (bytes + 255) & ~(size_t)255;
    return p;
  };
  _Float16* xb  = (_Float16*)alloc((size_t)MROW * DIMN * 2);   // 33.5 MB
  _Float16* wkb = (_Float16*)alloc((size_t)DIMN * DIMN * 2);   // 2 MB
  _Float16* wvb = (_Float16*)alloc((size_t)DIMN * DIMN * 2);
  _Float16* wob = (_Float16*)alloc((size_t)DIMN * DIMN * 2);
  float* Kb     = (float*)alloc((size_t)MROW * DIMN * 4);      // 67 MB (-> khat)
  float* Vb     = (float*)alloc((size_t)MROW * DIMN * 4);      // 67 MB (-> bound -> retrieved)
  float* segsum = (float*)alloc((size_t)BATCH * SEG * DIMN * 4);
  float* segoff = (float*)alloc((size_t)BATCH * SEG * DIMN * 4);
  _Float16* nb  = (_Float16*)alloc((size_t)MROW * DIMN * 2);   // 33.5 MB
  (void)off; (void)ws_size; (void)in_sizes; (void)n_in; (void)out_size;

  // casts
  k_cast_f16<<<MROW * DIMN / 4 / 256, 256, 0, stream>>>(x, xb, MROW * DIMN / 4);
  k_cast_f16<<<DIMN * DIMN / 4 / 256, 256, 0, stream>>>(Wk, wkb, DIMN * DIMN / 4);
  k_cast_f16<<<DIMN * DIMN / 4 / 256, 256, 0, stream>>>(Wv, wvb, DIMN * DIMN / 4);
  k_cast_f16<<<DIMN * DIMN / 4 / 256, 256, 0, stream>>>(Wo, wob, DIMN * DIMN / 4);

  // K and V projections
  k_gemm<<<(MROW / 128) * (DIMN / 128), 256, 0, stream>>>(xb, wkb, bk, nullptr, Kb);
  k_gemm<<<(MROW / 128) * (DIMN / 128), 256, 0, stream>>>(xb, wvb, bv, nullptr, Vb);

  // bind + segment sums; scan; retrieve
  k_bound_segsum<<<BATCH * SEG, 256, 0, stream>>>(Kb, Vb, segsum);
  k_segscan<<<BATCH * DIMN / 256, 256, 0, stream>>>(segsum, segoff);
  k_retrieve<<<BATCH * SEG, 256, 0, stream>>>(Kb, Vb, segoff);

  // LayerNorm -> fp16, then output GEMM with residual
  k_ln<<<MROW, 256, 0, stream>>>(Vb, ln_g, ln_b, nb);
  k_gemm<<<(MROW / 128) * (DIMN / 128), 256, 0, stream>>>(nb, wob, bo, x, out);
}

// Round 2
// 305.944 us; speedup vs baseline: 1.1727x; 1.1727x over previous
//
#include <hip/hip_runtime.h>
#include <cstdint>
#include <cstddef>

// ---------------------------------------------------------------------------
// QuaternionPhasorBlock.
// GEMMs: 256x256 tile, BK=64, 8 waves (2Mx4N), 4 phases/K-tile, double-buffered
// 128KB LDS, counted vmcnt (never 0 in loop), setprio around MFMA, XCD swizzle.
// K|V projections fused into one N=2048 GEMM.
// ---------------------------------------------------------------------------

typedef float    f32x4 __attribute__((ext_vector_type(4)));
typedef _Float16 f16x8 __attribute__((ext_vector_type(8)));
typedef _Float16 f16x4 __attribute__((ext_vector_type(4)));

#define DEV static __device__ __forceinline__

constexpr int BATCH = 4;
constexpr int LSEQ  = 4096;
constexpr int DIMN  = 1024;
constexpr int MROW  = BATCH * LSEQ;   // 16384
constexpr int SEG   = 64;
constexpr int SL    = LSEQ / SEG;     // 64
constexpr int NT    = DIMN / 64;      // 16 K-tiles of BK=64

DEV f32x4 qmul(f32x4 a, f32x4 b) {
  f32x4 r;
  r.x = a.x*b.x - a.y*b.y - a.z*b.z - a.w*b.w;
  r.y = a.x*b.y + a.y*b.x + a.z*b.w - a.w*b.z;
  r.z = a.x*b.z - a.y*b.w + a.z*b.x + a.w*b.y;
  r.w = a.x*b.w + a.y*b.z - a.z*b.y + a.w*b.x;
  return r;
}

// ---------------- fp32 -> fp16 cast ----------------
__global__ __launch_bounds__(256) void k_cast_f16(const float* __restrict__ in,
                                                  _Float16* __restrict__ out, int n4) {
  int i = blockIdx.x * 256 + threadIdx.x;
  if (i < n4) {
    f32x4 v = ((const f32x4*)in)[i];
    f16x4 o = { (_Float16)v.x, (_Float16)v.y, (_Float16)v.z, (_Float16)v.w };
    ((f16x4*)out)[i] = o;
  }
}

// ---------------- 256x256 GEMM: C[M][N] = A[M][1024] @ Bw[N][1024]^T -------
// Phases per K-tile (slot s active, staging tile T+1 into slot s^1):
//  P1: read A-half0 frags + B-half0 frags; stage (T+1).A0; vmcnt(2); bar; MFMA m0-3 x n0-1; bar
//  P2: read B-half1 frags;                 stage (T+1).B0;           bar; MFMA m0-3 x n2-3; bar
//  P3: read A-half1 frags;                 stage (T+1).A1;           bar; MFMA m4-7 x n0-1; bar
//  P4: (regs reused)                       stage (T+1).B1; vmcnt(4); bar; MFMA m4-7 x n2-3; bar
// vmcnt(4) @P4: outstanding = T+1's {A0,B0,A1,B1}=8 -> A0,B0 landed (read at P1').
// vmcnt(2) @P1: outstanding = T's {A1,B1} + new A0 = 6 -> A1,B1 landed (read P2/P3).
__global__ __launch_bounds__(512, 2) void k_gemm256(
    const _Float16* __restrict__ A, const _Float16* __restrict__ Bw,
    const float* __restrict__ biasA, const float* __restrict__ biasB, int nsplit,
    const float* __restrict__ resid, float* __restrict__ C, int ldC, int nbn) {
  extern __shared__ char smem[];
  const int tid  = threadIdx.x;
  const int lane = tid & 63;
  const int wid  = tid >> 6;
  const int wr = wid >> 2, wc = wid & 3;

  // XCD-aware bijective swizzle (grid % 8 == 0), bm-major chunks per XCD.
  const int nwg = gridDim.x;
  const int cpx = nwg >> 3;
  const int swz = (blockIdx.x & 7) * cpx + (blockIdx.x >> 3);
  const int bm = swz / nbn, bn = swz % nbn;

  auto regBase = [](int slot, int isB, int half) -> unsigned {
    return (unsigned)(((slot * 2 + isB) * 2 + half) * 16384);
  };
  const int r8    = lane >> 3;
  const int sslot = (lane & 7) ^ r8;   // pre-swizzled 16B source slot
  const char* aT = (const char*)(A  + (size_t)bm * 256 * DIMN);
  const char* bT = (const char*)(Bw + (size_t)bn * 256 * DIMN);

  auto stage = [&](int isB, int half, int slot, int kt) {
    const char* gb = (isB ? bT : aT) + (size_t)(half * 128) * 2048 + kt * 128;
    const unsigned reg = regBase(slot, isB, half);
#pragma unroll
    for (int i = 0; i < 2; ++i) {
      const int c = wid * 2 + i;  // 1KB chunk (16 per half-tile)
      const char* src = gb + (size_t)(c * 8 + r8) * 2048 + (sslot << 4);
      __builtin_amdgcn_global_load_lds(
          (const __attribute__((address_space(1))) void*)src,
          (__attribute__((address_space(3))) void*)(smem + reg + c * 1024), 16, 0, 0);
    }
  };
  auto fragA = [&](int slot, int m, int kk) -> f16x8 {
    const int half = m >> 2;
    const int row  = wr * 64 + (m & 3) * 16 + (lane & 15);
    const int sl   = (kk * 4 + (lane >> 4)) ^ (row & 7);
    return *(const f16x8*)(smem + regBase(slot, 0, half) + row * 128 + (sl << 4));
  };
  auto fragB = [&](int slot, int n, int kk) -> f16x8 {
    const int half = n >> 1;
    const int row  = wc * 32 + (n & 1) * 16 + (lane & 15);
    const int sl   = (kk * 4 + (lane >> 4)) ^ (row & 7);
    return *(const f16x8*)(smem + regBase(slot, 1, half) + row * 128 + (sl << 4));
  };

  f32x4 acc[8][4];
#pragma unroll
  for (int m = 0; m < 8; ++m)
#pragma unroll
    for (int n = 0; n < 4; ++n) acc[m][n] = (f32x4){0.f, 0.f, 0.f, 0.f};

  // prologue: stage tile 0 into slot 0 (order A0,B0,A1,B1)
  stage(0, 0, 0, 0); stage(1, 0, 0, 0); stage(0, 1, 0, 0); stage(1, 1, 0, 0);
  asm volatile("s_waitcnt vmcnt(4)" ::: "memory");
  __builtin_amdgcn_s_barrier();

  f16x8 a[4][2], b0[2][2], b1[2][2];
#pragma unroll 2
  for (int T = 0; T < NT; ++T) {
    const int slot = T & 1, ns = slot ^ 1;
    const bool pf = (T + 1 < NT);
    // ---- P1 ----
#pragma unroll
    for (int m = 0; m < 4; ++m) { a[m][0] = fragA(slot, m, 0); a[m][1] = fragA(slot, m, 1); }
#pragma unroll
    for (int n = 0; n < 2; ++n) { b0[n][0] = fragB(slot, n, 0); b0[n][1] = fragB(slot, n, 1); }
    if (pf) stage(0, 0, ns, T + 1);
    asm volatile("s_waitcnt vmcnt(2)" ::: "memory");
    __builtin_amdgcn_s_barrier();
    __builtin_amdgcn_s_setprio(1);
#pragma unroll
    for (int m = 0; m < 4; ++m)
#pragma unroll
      for (int n = 0; n < 2; ++n) {
        acc[m][n] = __builtin_amdgcn_mfma_f32_16x16x32_f16(a[m][0], b0[n][0], acc[m][n], 0, 0, 0);
        acc[m][n] = __builtin_amdgcn_mfma_f32_16x16x32_f16(a[m][1], b0[n][1], acc[m][n], 0, 0, 0);
      }
    __builtin_amdgcn_s_setprio(0);
    __builtin_amdgcn_s_barrier();
    // ---- P2 ----
#pragma unroll
    for (int n = 0; n < 2; ++n) { b1[n][0] = fragB(slot, n + 2, 0); b1[n][1] = fragB(slot, n + 2, 1); }
    if (pf) stage(1, 0, ns, T + 1);
    __builtin_amdgcn_s_barrier();
    __builtin_amdgcn_s_setprio(1);
#pragma unroll
    for (int m = 0; m < 4; ++m)
#pragma unroll
      for (int n = 0; n < 2; ++n) {
        acc[m][n + 2] = __builtin_amdgcn_mfma_f32_16x16x32_f16(a[m][0], b1[n][0], acc[m][n + 2], 0, 0, 0);
        acc[m][n + 2] = __builtin_amdgcn_mfma_f32_16x16x32_f16(a[m][1], b1[n][1], acc[m][n + 2], 0, 0, 0);
      }
    __builtin_amdgcn_s_setprio(0);
    __builtin_amdgcn_s_barrier();
    // ---- P3 ----
#pragma unroll
    for (int m = 0; m < 4; ++m) { a[m][0] = fragA(slot, m + 4, 0); a[m][1] = fragA(slot, m + 4, 1); }
    if (pf) stage(0, 1, ns, T + 1);
    __builtin_amdgcn_s_barrier();
    __builtin_amdgcn_s_setprio(1);
#pragma unroll
    for (int m = 0; m < 4; ++m)
#pragma unroll
      for (int n = 0; n < 2; ++n) {
        acc[m + 4][n] = __builtin_amdgcn_mfma_f32_16x16x32_f16(a[m][0], b0[n][0], acc[m + 4][n], 0, 0, 0);
        acc[m + 4][n] = __builtin_amdgcn_mfma_f32_16x16x32_f16(a[m][1], b0[n][1], acc[m + 4][n], 0, 0, 0);
      }
    __builtin_amdgcn_s_setprio(0);
    __builtin_amdgcn_s_barrier();
    // ---- P4 ----
    if (pf) stage(1, 1, ns, T + 1);
    asm volatile("s_waitcnt vmcnt(4)" ::: "memory");
    __builtin_amdgcn_s_barrier();
    __builtin_amdgcn_s_setprio(1);
#pragma unroll
    for (int m = 0; m < 4; ++m)
#pragma unroll
      for (int n = 0; n < 2; ++n) {
        acc[m + 4][n + 2] = __builtin_amdgcn_mfma_f32_16x16x32_f16(a[m][0], b1[n][0], acc[m + 4][n + 2], 0, 0, 0);
        acc[m + 4][n + 2] = __builtin_amdgcn_mfma_f32_16x16x32_f16(a[m][1], b1[n][1], acc[m + 4][n + 2], 0, 0, 0);
      }
    __builtin_amdgcn_s_setprio(0);
    __builtin_amdgcn_s_barrier();
  }

  // ---- epilogue: C/D frag layout col=lane&15, row=(lane>>4)*4+t ----
  const int r0 = bm * 256 + wr * 64 + ((lane >> 4) << 2);
  const int c0 = bn * 256 + wc * 32 + (lane & 15);
#pragma unroll
  for (int n = 0; n < 4; ++n) {
    const int col = c0 + (n >> 1) * 128 + (n & 1) * 16;
    const float bc = (col < nsplit) ? biasA[col] : biasB[col - nsplit];
#pragma unroll
    for (int m = 0; m < 8; ++m) {
      const int row = r0 + (m >> 2) * 128 + (m & 3) * 16;
#pragma unroll
      for (int t = 0; t < 4; ++t) {
        const size_t off = (size_t)(row + t) * ldC + col;
        float v = acc[m][n][t] + bc;
        if (resid) v += resid[(size_t)(row + t) * DIMN + col];
        C[off] = v;
      }
    }
  }
}

// ---------------- normalize keys, bind, per-segment sums (KV layout) -------
// KV: [row][2048] f32; cols 0..1023 = keys (-> khat), 1024..2047 = values (-> bound)
__global__ __launch_bounds__(256) void k_bound_segsum(float* __restrict__ KV,
                                                      float* __restrict__ segsum) {
  const int b = blockIdx.x >> 6, seg = blockIdx.x & 63, n = threadIdx.x;
  f32x4 ssum = (f32x4){0.f, 0.f, 0.f, 0.f};
  const size_t rb = (size_t)(b * LSEQ + seg * SL) * 2048 + n * 4;
  for (int l = 0; l < SL; ++l) {
    const size_t p = rb + (size_t)l * 2048;
    f32x4 kq = *(const f32x4*)(KV + p);
    f32x4 vq = *(const f32x4*)(KV + p + 1024);
    float nn = sqrtf(kq.x*kq.x + kq.y*kq.y + kq.z*kq.z + kq.w*kq.w);
    f32x4 kh = kq * (1.0f / fmaxf(nn, 1e-12f));
    f32x4 bd = qmul(vq, kh);
    *(f32x4*)(KV + p) = kh;
    *(f32x4*)(KV + p + 1024) = bd;
    ssum += bd;
  }
  ((f32x4*)segsum)[(size_t)blockIdx.x * 256 + n] = ssum;
}

// ---------------- exclusive scan of segment sums ---------------------------
__global__ __launch_bounds__(256) void k_segscan(const float* __restrict__ segsum,
                                                 float* __restrict__ segoff) {
  const int gt = blockIdx.x * 256 + threadIdx.x;  // 0..4095
  const int b = gt >> 10, ch = gt & 1023;
  float run = 0.f;
  for (int s = 0; s < SEG; ++s) {
    const size_t idx = ((size_t)(b * SEG + s)) * 1024 + ch;
    float v = segsum[idx];
    segoff[idx] = run;
    run += v;
  }
}

// ---------------- in-segment scan + retrieve (in place in V half) ----------
__global__ __launch_bounds__(256) void k_retrieve(float* __restrict__ KV,
                                                  const float* __restrict__ segoff) {
  const int b = blockIdx.x >> 6, seg = blockIdx.x & 63, n = threadIdx.x;
  f32x4 mem = ((const f32x4*)segoff)[(size_t)blockIdx.x * 256 + n];
  const size_t rb = (size_t)(b * LSEQ + seg * SL) * 2048 + n * 4;
  for (int l = 0; l < SL; ++l) {
    const size_t p = rb + (size_t)l * 2048;
    f32x4 bd = *(const f32x4*)(KV + p + 1024);
    f32x4 kh = *(const f32x4*)(KV + p);
    mem += bd;
    f32x4 kc = (f32x4){kh.x, -kh.y, -kh.z, -kh.w};
    f32x4 r = qmul(mem, kc);
    const int gl = seg * SL + l;
    r *= rsqrtf((float)(gl + 1));
    *(f32x4*)(KV + p + 1024) = r;
  }
}

// ---------------- LayerNorm over D=1024 -> fp16 ----------------------------
__global__ __launch_bounds__(256) void k_ln(const float* __restrict__ KV,
                                            const float* __restrict__ g,
                                            const float* __restrict__ bb,
                                            _Float16* __restrict__ out) {
  const int row = blockIdx.x, t = threadIdx.x;
  f32x4 v = *(const f32x4*)(KV + (size_t)row * 2048 + 1024 + t * 4);
  float s1 = v.x + v.y + v.z + v.w;
  float s2 = v.x*v.x + v.y*v.y + v.z*v.z + v.w*v.w;
#pragma unroll
  for (int off = 32; off > 0; off >>= 1) {
    s1 += __shfl_down(s1, off, 64);
    s2 += __shfl_down(s2, off, 64);
  }
  __shared__ float p1[4], p2[4];
  const int wid = t >> 6, lane = t & 63;
  if (lane == 0) { p1[wid] = s1; p2[wid] = s2; }
  __syncthreads();
  const float ts1 = p1[0] + p1[1] + p1[2] + p1[3];
  const float ts2 = p2[0] + p2[1] + p2[2] + p2[3];
  const float mu = ts1 * (1.0f / 1024.0f);
  const float var = ts2 * (1.0f / 1024.0f) - mu * mu;
  const float rstd = rsqrtf(var + 1e-5f);
  f32x4 gg = ((const f32x4*)g)[t];
  f32x4 bv = ((const f32x4*)bb)[t];
  f32x4 nv = (v - mu) * rstd * gg + bv;
  f16x4 o = { (_Float16)nv.x, (_Float16)nv.y, (_Float16)nv.z, (_Float16)nv.w };
  ((f16x4*)out)[(size_t)row * 256 + t] = o;
}

// ---------------------------------------------------------------------------
extern "C" void kernel_launch(void* const* d_in, const int* in_sizes, int n_in,
                              void* d_out, int out_size, void* d_ws, size_t ws_size,
                              hipStream_t stream) {
  const float* x    = (const float*)d_in[0];
  const float* Wk   = (const float*)d_in[1];
  const float* bk   = (const float*)d_in[2];
  const float* Wv   = (const float*)d_in[3];
  const float* bv   = (const float*)d_in[4];
  const float* ln_g = (const float*)d_in[5];
  const float* ln_b = (const float*)d_in[6];
  const float* Wo   = (const float*)d_in[7];
  const float* bo   = (const float*)d_in[8];
  float* out = (float*)d_out;

  char* ws = (char*)d_ws;
  size_t off = 0;
  auto alloc = [&](size_t bytes) -> void* {
    void* p = ws + off;
    off += (bytes + 255) & ~(size_t)255;
    return p;
  };
  _Float16* xb   = (_Float16*)alloc((size_t)MROW * DIMN * 2);       // 33.5 MB
  _Float16* wkvb = (_Float16*)alloc((size_t)2 * DIMN * DIMN * 2);   // 4 MB (Wk||Wv)
  _Float16* wob  = (_Float16*)alloc((size_t)DIMN * DIMN * 2);       // 2 MB
  float* KV      = (float*)alloc((size_t)MROW * 2 * DIMN * 4);      // 134 MB
  float* segsum  = (float*)alloc((size_t)BATCH * SEG * DIMN * 4);
  float* segoff  = (float*)alloc((size_t)BATCH * SEG * DIMN * 4);
  _Float16* nb   = (_Float16*)alloc((size_t)MROW * DIMN * 2);       // 33.5 MB
  (void)off; (void)ws_size; (void)in_sizes; (void)n_in; (void)out_size;

  hipFuncSetAttribute((const void*)k_gemm256,
                      hipFuncAttributeMaxDynamicSharedMemorySize, 131072);

  // casts
  k_cast_f16<<<MROW * DIMN / 4 / 256, 256, 0, stream>>>(x, xb, MROW * DIMN / 4);
  k_cast_f16<<<DIMN * DIMN / 4 / 256, 256, 0, stream>>>(Wk, wkvb, DIMN * DIMN / 4);
  k_cast_f16<<<DIMN * DIMN / 4 / 256, 256, 0, stream>>>(Wv, wkvb + (size_t)DIMN * DIMN, DIMN * DIMN / 4);
  k_cast_f16<<<DIMN * DIMN / 4 / 256, 256, 0, stream>>>(Wo, wob, DIMN * DIMN / 4);

  // fused K|V projection: [16384][2048] = xb @ (Wk||Wv)^T
  k_gemm256<<<(MROW / 256) * (2048 / 256), 512, 131072, stream>>>(
      xb, wkvb, bk, bv, 1024, nullptr, KV, 2048, 2048 / 256);

  // bind + segment sums; scan; retrieve
  k_bound_segsum<<<BATCH * SEG, 256, 0, stream>>>(KV, segsum);
  k_segscan<<<BATCH * DIMN / 256, 256, 0, stream>>>(segsum, segoff);
  k_retrieve<<<BATCH * SEG, 256, 0, stream>>>(KV, segoff);

  // LayerNorm -> fp16, output GEMM with residual
  k_ln<<<MROW, 256, 0, stream>>>(KV, ln_g, ln_b, nb);
  k_gemm256<<<(MROW / 256) * (DIMN / 256), 512, 131072, stream>>>(
      nb, wob, bo, bo, 4 * DIMN, x, out, 1024, DIMN / 256);
}

// Round 3
// 256.693 us; speedup vs baseline: 1.3977x; 1.1919x over previous
//
#include <hip/hip_runtime.h>
#include <cstdint>
#include <cstddef>

// ---------------------------------------------------------------------------
// QuaternionPhasorBlock.
// KV GEMM: 256x256 tile (proven 613 TF). OUT GEMM: 128x256 tile, 2-phase
// counted-vmcnt, 96KB LDS, grid 512 (2 pipelined rounds). Elementwise:
// segsum (recompute bind) -> segscan -> retrieve+LN fused (recompute bind).
// ---------------------------------------------------------------------------

typedef float    f32x4 __attribute__((ext_vector_type(4)));
typedef _Float16 f16x8 __attribute__((ext_vector_type(8)));
typedef _Float16 f16x4 __attribute__((ext_vector_type(4)));

#define DEV static __device__ __forceinline__

constexpr int BATCH = 4;
constexpr int LSEQ  = 4096;
constexpr int DIMN  = 1024;
constexpr int MROW  = BATCH * LSEQ;   // 16384
constexpr int SEG   = 64;
constexpr int SL    = LSEQ / SEG;     // 64
constexpr int NT    = DIMN / 64;      // 16 K-tiles of BK=64

DEV f32x4 qmul(f32x4 a, f32x4 b) {
  f32x4 r;
  r.x = a.x*b.x - a.y*b.y - a.z*b.z - a.w*b.w;
  r.y = a.x*b.y + a.y*b.x + a.z*b.w - a.w*b.z;
  r.z = a.x*b.z - a.y*b.w + a.z*b.x + a.w*b.y;
  r.w = a.x*b.w + a.y*b.z - a.z*b.y + a.w*b.x;
  return r;
}

// ---------------- fp32 -> fp16 cast ----------------
__global__ __launch_bounds__(256) void k_cast_f16(const float* __restrict__ in,
                                                  _Float16* __restrict__ out, int n4) {
  int i = blockIdx.x * 256 + threadIdx.x;
  if (i < n4) {
    f32x4 v = ((const f32x4*)in)[i];
    f16x4 o = { (_Float16)v.x, (_Float16)v.y, (_Float16)v.z, (_Float16)v.w };
    ((f16x4*)out)[i] = o;
  }
}

// ---------------- 256x256 GEMM (KV projection; unchanged, proven) ----------
__global__ __launch_bounds__(512, 2) void k_gemm256(
    const _Float16* __restrict__ A, const _Float16* __restrict__ Bw,
    const float* __restrict__ biasA, const float* __restrict__ biasB, int nsplit,
    const float* __restrict__ resid, float* __restrict__ C, int ldC, int nbn) {
  extern __shared__ char smem[];
  const int tid  = threadIdx.x;
  const int lane = tid & 63;
  const int wid  = tid >> 6;
  const int wr = wid >> 2, wc = wid & 3;

  const int nwg = gridDim.x;
  const int cpx = nwg >> 3;
  const int swz = (blockIdx.x & 7) * cpx + (blockIdx.x >> 3);
  const int bm = swz / nbn, bn = swz % nbn;

  auto regBase = [](int slot, int isB, int half) -> unsigned {
    return (unsigned)(((slot * 2 + isB) * 2 + half) * 16384);
  };
  const int r8    = lane >> 3;
  const int sslot = (lane & 7) ^ r8;
  const char* aT = (const char*)(A  + (size_t)bm * 256 * DIMN);
  const char* bT = (const char*)(Bw + (size_t)bn * 256 * DIMN);

  auto stage = [&](int isB, int half, int slot, int kt) {
    const char* gb = (isB ? bT : aT) + (size_t)(half * 128) * 2048 + kt * 128;
    const unsigned reg = regBase(slot, isB, half);
#pragma unroll
    for (int i = 0; i < 2; ++i) {
      const int c = wid * 2 + i;
      const char* src = gb + (size_t)(c * 8 + r8) * 2048 + (sslot << 4);
      __builtin_amdgcn_global_load_lds(
          (const __attribute__((address_space(1))) void*)src,
          (__attribute__((address_space(3))) void*)(smem + reg + c * 1024), 16, 0, 0);
    }
  };
  auto fragA = [&](int slot, int m, int kk) -> f16x8 {
    const int half = m >> 2;
    const int row  = wr * 64 + (m & 3) * 16 + (lane & 15);
    const int sl   = (kk * 4 + (lane >> 4)) ^ (row & 7);
    return *(const f16x8*)(smem + regBase(slot, 0, half) + row * 128 + (sl << 4));
  };
  auto fragB = [&](int slot, int n, int kk) -> f16x8 {
    const int half = n >> 1;
    const int row  = wc * 32 + (n & 1) * 16 + (lane & 15);
    const int sl   = (kk * 4 + (lane >> 4)) ^ (row & 7);
    return *(const f16x8*)(smem + regBase(slot, 1, half) + row * 128 + (sl << 4));
  };

  f32x4 acc[8][4];
#pragma unroll
  for (int m = 0; m < 8; ++m)
#pragma unroll
    for (int n = 0; n < 4; ++n) acc[m][n] = (f32x4){0.f, 0.f, 0.f, 0.f};

  stage(0, 0, 0, 0); stage(1, 0, 0, 0); stage(0, 1, 0, 0); stage(1, 1, 0, 0);
  asm volatile("s_waitcnt vmcnt(4)" ::: "memory");
  __builtin_amdgcn_s_barrier();

  f16x8 a[4][2], b0[2][2], b1[2][2];
#pragma unroll 2
  for (int T = 0; T < NT; ++T) {
    const int slot = T & 1, ns = slot ^ 1;
    const bool pf = (T + 1 < NT);
    // ---- P1 ----
#pragma unroll
    for (int m = 0; m < 4; ++m) { a[m][0] = fragA(slot, m, 0); a[m][1] = fragA(slot, m, 1); }
#pragma unroll
    for (int n = 0; n < 2; ++n) { b0[n][0] = fragB(slot, n, 0); b0[n][1] = fragB(slot, n, 1); }
    if (pf) stage(0, 0, ns, T + 1);
    asm volatile("s_waitcnt vmcnt(2)" ::: "memory");
    __builtin_amdgcn_s_barrier();
    __builtin_amdgcn_s_setprio(1);
#pragma unroll
    for (int m = 0; m < 4; ++m)
#pragma unroll
      for (int n = 0; n < 2; ++n) {
        acc[m][n] = __builtin_amdgcn_mfma_f32_16x16x32_f16(a[m][0], b0[n][0], acc[m][n], 0, 0, 0);
        acc[m][n] = __builtin_amdgcn_mfma_f32_16x16x32_f16(a[m][1], b0[n][1], acc[m][n], 0, 0, 0);
      }
    __builtin_amdgcn_s_setprio(0);
    __builtin_amdgcn_s_barrier();
    // ---- P2 ----
#pragma unroll
    for (int n = 0; n < 2; ++n) { b1[n][0] = fragB(slot, n + 2, 0); b1[n][1] = fragB(slot, n + 2, 1); }
    if (pf) stage(1, 0, ns, T + 1);
    __builtin_amdgcn_s_barrier();
    __builtin_amdgcn_s_setprio(1);
#pragma unroll
    for (int m = 0; m < 4; ++m)
#pragma unroll
      for (int n = 0; n < 2; ++n) {
        acc[m][n + 2] = __builtin_amdgcn_mfma_f32_16x16x32_f16(a[m][0], b1[n][0], acc[m][n + 2], 0, 0, 0);
        acc[m][n + 2] = __builtin_amdgcn_mfma_f32_16x16x32_f16(a[m][1], b1[n][1], acc[m][n + 2], 0, 0, 0);
      }
    __builtin_amdgcn_s_setprio(0);
    __builtin_amdgcn_s_barrier();
    // ---- P3 ----
#pragma unroll
    for (int m = 0; m < 4; ++m) { a[m][0] = fragA(slot, m + 4, 0); a[m][1] = fragA(slot, m + 4, 1); }
    if (pf) stage(0, 1, ns, T + 1);
    __builtin_amdgcn_s_barrier();
    __builtin_amdgcn_s_setprio(1);
#pragma unroll
    for (int m = 0; m < 4; ++m)
#pragma unroll
      for (int n = 0; n < 2; ++n) {
        acc[m + 4][n] = __builtin_amdgcn_mfma_f32_16x16x32_f16(a[m][0], b0[n][0], acc[m + 4][n], 0, 0, 0);
        acc[m + 4][n] = __builtin_amdgcn_mfma_f32_16x16x32_f16(a[m][1], b0[n][1], acc[m + 4][n], 0, 0, 0);
      }
    __builtin_amdgcn_s_setprio(0);
    __builtin_amdgcn_s_barrier();
    // ---- P4 ----
    if (pf) stage(1, 1, ns, T + 1);
    asm volatile("s_waitcnt vmcnt(4)" ::: "memory");
    __builtin_amdgcn_s_barrier();
    __builtin_amdgcn_s_setprio(1);
#pragma unroll
    for (int m = 0; m < 4; ++m)
#pragma unroll
      for (int n = 0; n < 2; ++n) {
        acc[m + 4][n + 2] = __builtin_amdgcn_mfma_f32_16x16x32_f16(a[m][0], b1[n][0], acc[m + 4][n + 2], 0, 0, 0);
        acc[m + 4][n + 2] = __builtin_amdgcn_mfma_f32_16x16x32_f16(a[m][1], b1[n][1], acc[m + 4][n + 2], 0, 0, 0);
      }
    __builtin_amdgcn_s_setprio(0);
    __builtin_amdgcn_s_barrier();
  }

  const int r0 = bm * 256 + wr * 64 + ((lane >> 4) << 2);
  const int c0 = bn * 256 + wc * 32 + (lane & 15);
#pragma unroll
  for (int n = 0; n < 4; ++n) {
    const int col = c0 + (n >> 1) * 128 + (n & 1) * 16;
    const float bc = (col < nsplit) ? biasA[col] : biasB[col - nsplit];
#pragma unroll
    for (int m = 0; m < 8; ++m) {
      const int row = r0 + (m >> 2) * 128 + (m & 3) * 16;
#pragma unroll
      for (int t = 0; t < 4; ++t) {
        const size_t off = (size_t)(row + t) * ldC + col;
        float v = acc[m][n][t] + bc;
        if (resid) v += resid[(size_t)(row + t) * DIMN + col];
        C[off] = v;
      }
    }
  }
}

// ---------------- 128x256 GEMM (output projection), 2-phase counted --------
// LDS 96KB: A 2x16KB @0, B 2slots x 2half x 16KB @32768. Grid = 512 blocks.
// P1: read A+B0 frags; stage A',B0'; vmcnt(4) [drains B1(T)]; bar; 16 MFMA; bar
// P2: read B1 frags;   stage B1';    vmcnt(2) [drains A',B0']; bar; 16 MFMA; bar
__global__ __launch_bounds__(512, 2) void k_gemm128(
    const _Float16* __restrict__ A, const _Float16* __restrict__ Bw,
    const float* __restrict__ bias, const float* __restrict__ resid,
    float* __restrict__ C, int nbn) {
  extern __shared__ char smem[];
  const int tid  = threadIdx.x;
  const int lane = tid & 63;
  const int wid  = tid >> 6;
  const int wr = wid >> 2, wc = wid & 3;

  const int nwg = gridDim.x;
  const int cpx = nwg >> 3;
  const int swz = (blockIdx.x & 7) * cpx + (blockIdx.x >> 3);
  const int bm = swz / nbn, bn = swz % nbn;

  const int r8    = lane >> 3;
  const int sslot = (lane & 7) ^ r8;
  const char* aT = (const char*)(A  + (size_t)bm * 128 * DIMN);
  const char* bT = (const char*)(Bw + (size_t)bn * 256 * DIMN);

  auto stageA = [&](int slot, int kt) {
    const char* gb = aT + kt * 128;
    char* dst = smem + slot * 16384;
#pragma unroll
    for (int i = 0; i < 2; ++i) {
      const int c = wid * 2 + i;
      const char* src = gb + (size_t)(c * 8 + r8) * 2048 + (sslot << 4);
      __builtin_amdgcn_global_load_lds(
          (const __attribute__((address_space(1))) void*)src,
          (__attribute__((address_space(3))) void*)(dst + c * 1024), 16, 0, 0);
    }
  };
  auto stageB = [&](int slot, int half, int kt) {
    const char* gb = bT + (size_t)(half * 128) * 2048 + kt * 128;
    char* dst = smem + 32768 + (slot * 2 + half) * 16384;
#pragma unroll
    for (int i = 0; i < 2; ++i) {
      const int c = wid * 2 + i;
      const char* src = gb + (size_t)(c * 8 + r8) * 2048 + (sslot << 4);
      __builtin_amdgcn_global_load_lds(
          (const __attribute__((address_space(1))) void*)src,
          (__attribute__((address_space(3))) void*)(dst + c * 1024), 16, 0, 0);
    }
  };
  auto fragA = [&](int slot, int m, int kk) -> f16x8 {
    const int row = wr * 64 + m * 16 + (lane & 15);          // 0..127
    const int sl  = (kk * 4 + (lane >> 4)) ^ (row & 7);
    return *(const f16x8*)(smem + slot * 16384 + row * 128 + (sl << 4));
  };
  auto fragB = [&](int slot, int n, int kk) -> f16x8 {
    const int half = n >> 1;
    const int lrow = wc * 32 + (n & 1) * 16 + (lane & 15);   // 0..127
    const int sl   = (kk * 4 + (lane >> 4)) ^ (lrow & 7);
    return *(const f16x8*)(smem + 32768 + (slot * 2 + half) * 16384 + lrow * 128 + (sl << 4));
  };

  f32x4 acc[4][4];
#pragma unroll
  for (int m = 0; m < 4; ++m)
#pragma unroll
    for (int n = 0; n < 4; ++n) acc[m][n] = (f32x4){0.f, 0.f, 0.f, 0.f};

  // prologue: tile 0 (A, B0, B1); drain A,B0 only
  stageA(0, 0); stageB(0, 0, 0); stageB(0, 1, 0);
  asm volatile("s_waitcnt vmcnt(2)" ::: "memory");
  __builtin_amdgcn_s_barrier();

  f16x8 a[4][2], b0[2][2], b1[2][2];
#pragma unroll 2
  for (int T = 0; T < NT; ++T) {
    const int slot = T & 1, ns = slot ^ 1;
    const bool pf = (T + 1 < NT);
    // ---- P1 ----
#pragma unroll
    for (int m = 0; m < 4; ++m) { a[m][0] = fragA(slot, m, 0); a[m][1] = fragA(slot, m, 1); }
#pragma unroll
    for (int n = 0; n < 2; ++n) { b0[n][0] = fragB(slot, n, 0); b0[n][1] = fragB(slot, n, 1); }
    if (pf) {
      stageA(ns, T + 1); stageB(ns, 0, T + 1);
      asm volatile("s_waitcnt vmcnt(4)" ::: "memory");
    } else {
      asm volatile("s_waitcnt vmcnt(0)" ::: "memory");
    }
    __builtin_amdgcn_s_barrier();
    __builtin_amdgcn_s_setprio(1);
#pragma unroll
    for (int m = 0; m < 4; ++m)
#pragma unroll
      for (int n = 0; n < 2; ++n) {
        acc[m][n] = __builtin_amdgcn_mfma_f32_16x16x32_f16(a[m][0], b0[n][0], acc[m][n], 0, 0, 0);
        acc[m][n] = __builtin_amdgcn_mfma_f32_16x16x32_f16(a[m][1], b0[n][1], acc[m][n], 0, 0, 0);
      }
    __builtin_amdgcn_s_setprio(0);
    __builtin_amdgcn_s_barrier();
    // ---- P2 ----
#pragma unroll
    for (int n = 0; n < 2; ++n) { b1[n][0] = fragB(slot, n + 2, 0); b1[n][1] = fragB(slot, n + 2, 1); }
    if (pf) {
      stageB(ns, 1, T + 1);
      asm volatile("s_waitcnt vmcnt(2)" ::: "memory");
    }
    __builtin_amdgcn_s_barrier();
    __builtin_amdgcn_s_setprio(1);
#pragma unroll
    for (int m = 0; m < 4; ++m)
#pragma unroll
      for (int n = 0; n < 2; ++n) {
        acc[m][n + 2] = __builtin_amdgcn_mfma_f32_16x16x32_f16(a[m][0], b1[n][0], acc[m][n + 2], 0, 0, 0);
        acc[m][n + 2] = __builtin_amdgcn_mfma_f32_16x16x32_f16(a[m][1], b1[n][1], acc[m][n + 2], 0, 0, 0);
      }
    __builtin_amdgcn_s_setprio(0);
    __builtin_amdgcn_s_barrier();
  }

  const int r0 = bm * 128 + wr * 64 + ((lane >> 4) << 2);
  const int c0 = bn * 256 + wc * 32 + (lane & 15);
#pragma unroll
  for (int n = 0; n < 4; ++n) {
    const int col = c0 + (n >> 1) * 128 + (n & 1) * 16;
    const float bc = bias[col];
#pragma unroll
    for (int m = 0; m < 4; ++m) {
      const int row = r0 + m * 16;
#pragma unroll
      for (int t = 0; t < 4; ++t) {
        const size_t off = (size_t)(row + t) * DIMN + col;
        C[off] = acc[m][n][t] + bc + resid[off];
      }
    }
  }
}

// ---------------- segment sums (recompute normalize+bind, no KV writes) ----
__global__ __launch_bounds__(256) void k_segsum(const float* __restrict__ KV,
                                                float* __restrict__ segsum) {
  const int b = blockIdx.x >> 6, seg = blockIdx.x & 63, n = threadIdx.x;
  f32x4 ssum = (f32x4){0.f, 0.f, 0.f, 0.f};
  const size_t rb = (size_t)(b * LSEQ + seg * SL) * 2048 + n * 4;
  for (int l = 0; l < SL; ++l) {
    const size_t p = rb + (size_t)l * 2048;
    f32x4 kq = *(const f32x4*)(KV + p);
    f32x4 vq = *(const f32x4*)(KV + p + 1024);
    float nn = sqrtf(kq.x*kq.x + kq.y*kq.y + kq.z*kq.z + kq.w*kq.w);
    f32x4 kh = kq * (1.0f / fmaxf(nn, 1e-12f));
    ssum += qmul(vq, kh);
  }
  ((f32x4*)segsum)[(size_t)blockIdx.x * 256 + n] = ssum;
}

// ---------------- exclusive scan of segment sums ---------------------------
__global__ __launch_bounds__(256) void k_segscan(const float* __restrict__ segsum,
                                                 float* __restrict__ segoff) {
  const int gt = blockIdx.x * 256 + threadIdx.x;  // 0..4095
  const int b = gt >> 10, ch = gt & 1023;
  float run = 0.f;
  for (int s = 0; s < SEG; ++s) {
    const size_t idx = ((size_t)(b * SEG + s)) * 1024 + ch;
    float v = segsum[idx];
    segoff[idx] = run;
    run += v;
  }
}

// ---------------- retrieve + LayerNorm fused (recompute bind) --------------
// Block = (b, seg); 256 threads = 256 quats = full row. Per row: scan step,
// retrieve, block-reduce mean/var, LN, write fp16.
__global__ __launch_bounds__(256) void k_retrieve_ln(
    const float* __restrict__ KV, const float* __restrict__ segoff,
    const float* __restrict__ g, const float* __restrict__ bb,
    _Float16* __restrict__ out) {
  const int b = blockIdx.x >> 6, seg = blockIdx.x & 63, n = threadIdx.x;
  const int wid = n >> 6, lane = n & 63;
  __shared__ float p1[2][4], p2[2][4];
  f32x4 mem = ((const f32x4*)segoff)[(size_t)blockIdx.x * 256 + n];
  const f32x4 gg  = ((const f32x4*)g)[n];
  const f32x4 bvv = ((const f32x4*)bb)[n];
  const size_t rb = (size_t)(b * LSEQ + seg * SL) * 2048 + n * 4;
  const int grow = b * LSEQ + seg * SL;

  f32x4 kq = *(const f32x4*)(KV + rb);
  f32x4 vq = *(const f32x4*)(KV + rb + 1024);
  for (int l = 0; l < SL; ++l) {
    f32x4 kqn, vqn;
    if (l + 1 < SL) {  // prefetch next row before the barrier
      kqn = *(const f32x4*)(KV + rb + (size_t)(l + 1) * 2048);
      vqn = *(const f32x4*)(KV + rb + (size_t)(l + 1) * 2048 + 1024);
    }
    float nn = sqrtf(kq.x*kq.x + kq.y*kq.y + kq.z*kq.z + kq.w*kq.w);
    f32x4 kh = kq * (1.0f / fmaxf(nn, 1e-12f));
    mem += qmul(vq, kh);
    f32x4 kc = (f32x4){kh.x, -kh.y, -kh.z, -kh.w};
    f32x4 r = qmul(mem, kc);
    r *= rsqrtf((float)(seg * SL + l + 1));

    float s1 = r.x + r.y + r.z + r.w;
    float s2 = r.x*r.x + r.y*r.y + r.z*r.z + r.w*r.w;
#pragma unroll
    for (int off = 32; off > 0; off >>= 1) {
      s1 += __shfl_down(s1, off, 64);
      s2 += __shfl_down(s2, off, 64);
    }
    if (lane == 0) { p1[l & 1][wid] = s1; p2[l & 1][wid] = s2; }
    __syncthreads();
    const float ts1 = p1[l & 1][0] + p1[l & 1][1] + p1[l & 1][2] + p1[l & 1][3];
    const float ts2 = p2[l & 1][0] + p2[l & 1][1] + p2[l & 1][2] + p2[l & 1][3];
    const float mu = ts1 * (1.0f / 1024.0f);
    const float var = ts2 * (1.0f / 1024.0f) - mu * mu;
    const float rstd = rsqrtf(var + 1e-5f);
    f32x4 nv = (r - mu) * rstd * gg + bvv;
    f16x4 o = { (_Float16)nv.x, (_Float16)nv.y, (_Float16)nv.z, (_Float16)nv.w };
    ((f16x4*)out)[(size_t)(grow + l) * 256 + n] = o;
    kq = kqn; vq = vqn;
  }
}

// ---------------------------------------------------------------------------
extern "C" void kernel_launch(void* const* d_in, const int* in_sizes, int n_in,
                              void* d_out, int out_size, void* d_ws, size_t ws_size,
                              hipStream_t stream) {
  const float* x    = (const float*)d_in[0];
  const float* Wk   = (const float*)d_in[1];
  const float* bk   = (const float*)d_in[2];
  const float* Wv   = (const float*)d_in[3];
  const float* bv   = (const float*)d_in[4];
  const float* ln_g = (const float*)d_in[5];
  const float* ln_b = (const float*)d_in[6];
  const float* Wo   = (const float*)d_in[7];
  const float* bo   = (const float*)d_in[8];
  float* out = (float*)d_out;

  char* ws = (char*)d_ws;
  size_t off = 0;
  auto alloc = [&](size_t bytes) -> void* {
    void* p = ws + off;
    off += (bytes + 255) & ~(size_t)255;
    return p;
  };
  _Float16* xb   = (_Float16*)alloc((size_t)MROW * DIMN * 2);       // 33.5 MB
  _Float16* wkvb = (_Float16*)alloc((size_t)2 * DIMN * DIMN * 2);   // 4 MB
  _Float16* wob  = (_Float16*)alloc((size_t)DIMN * DIMN * 2);       // 2 MB
  float* KV      = (float*)alloc((size_t)MROW * 2 * DIMN * 4);      // 134 MB (raw K|V)
  float* segsum  = (float*)alloc((size_t)BATCH * SEG * DIMN * 4);
  float* segoff  = (float*)alloc((size_t)BATCH * SEG * DIMN * 4);
  _Float16* nb   = (_Float16*)alloc((size_t)MROW * DIMN * 2);       // 33.5 MB
  (void)off; (void)ws_size; (void)in_sizes; (void)n_in; (void)out_size;

  hipFuncSetAttribute((const void*)k_gemm256,
                      hipFuncAttributeMaxDynamicSharedMemorySize, 131072);
  hipFuncSetAttribute((const void*)k_gemm128,
                      hipFuncAttributeMaxDynamicSharedMemorySize, 98304);

  // casts
  k_cast_f16<<<MROW * DIMN / 4 / 256, 256, 0, stream>>>(x, xb, MROW * DIMN / 4);
  k_cast_f16<<<DIMN * DIMN / 4 / 256, 256, 0, stream>>>(Wk, wkvb, DIMN * DIMN / 4);
  k_cast_f16<<<DIMN * DIMN / 4 / 256, 256, 0, stream>>>(Wv, wkvb + (size_t)DIMN * DIMN, DIMN * DIMN / 4);
  k_cast_f16<<<DIMN * DIMN / 4 / 256, 256, 0, stream>>>(Wo, wob, DIMN * DIMN / 4);

  // fused K|V projection: [16384][2048] = xb @ (Wk||Wv)^T
  k_gemm256<<<(MROW / 256) * (2048 / 256), 512, 131072, stream>>>(
      xb, wkvb, bk, bv, 1024, nullptr, KV, 2048, 2048 / 256);

  // segment sums (recompute bind) -> scan -> retrieve+LN
  k_segsum<<<BATCH * SEG, 256, 0, stream>>>(KV, segsum);
  k_segscan<<<BATCH * DIMN / 256, 256, 0, stream>>>(segsum, segoff);
  k_retrieve_ln<<<BATCH * SEG, 256, 0, stream>>>(KV, segoff, ln_g, ln_b, nb);

  // output GEMM with residual: 128x256 tiles, grid 512
  k_gemm128<<<(MROW / 128) * (DIMN / 256), 512, 98304, stream>>>(
      nb, wob, bo, x, out, DIMN / 256);
}

// Round 4
// 207.164 us; speedup vs baseline: 1.7319x; 1.2391x over previous
//
#include <hip/hip_runtime.h>
#include <cstdint>
#include <cstddef>

// ---------------------------------------------------------------------------
// QuaternionPhasorBlock.
// KV GEMM: 256x256, 4-phase, all-stages-at-P1 (deep prefetch), gates vmcnt(8)@P1
// /vmcnt(4)@P4, fp16 output. OUT GEMM: 128x256, 3 LDS slots (144KB), prefetch
// 2 tiles ahead, single vmcnt(6) gate per tile. Elementwise on fp16 KV.
// ---------------------------------------------------------------------------

typedef float    f32x4 __attribute__((ext_vector_type(4)));
typedef _Float16 f16x8 __attribute__((ext_vector_type(8)));
typedef _Float16 f16x4 __attribute__((ext_vector_type(4)));

#define DEV static __device__ __forceinline__

constexpr int BATCH = 4;
constexpr int LSEQ  = 4096;
constexpr int DIMN  = 1024;
constexpr int MROW  = BATCH * LSEQ;   // 16384
constexpr int SEG   = 128;
constexpr int SL    = LSEQ / SEG;     // 32
constexpr int NT    = DIMN / 64;      // 16 K-tiles of BK=64

DEV f32x4 qmul(f32x4 a, f32x4 b) {
  f32x4 r;
  r.x = a.x*b.x - a.y*b.y - a.z*b.z - a.w*b.w;
  r.y = a.x*b.y + a.y*b.x + a.z*b.w - a.w*b.z;
  r.z = a.x*b.z - a.y*b.w + a.z*b.x + a.w*b.y;
  r.w = a.x*b.w + a.y*b.z - a.z*b.y + a.w*b.x;
  return r;
}

DEV f32x4 h2f(f16x4 h) {
  return (f32x4){(float)h.x, (float)h.y, (float)h.z, (float)h.w};
}

// ---------------- fp32 -> fp16 cast (x) ----------------
__global__ __launch_bounds__(256) void k_cast_f16(const float* __restrict__ in,
                                                  _Float16* __restrict__ out, int n4) {
  int i = blockIdx.x * 256 + threadIdx.x;
  if (i < n4) {
    f32x4 v = ((const f32x4*)in)[i];
    f16x4 o = { (_Float16)v.x, (_Float16)v.y, (_Float16)v.z, (_Float16)v.w };
    ((f16x4*)out)[i] = o;
  }
}

// ---------------- fused cast of Wk,Wv,Wo into contiguous fp16 --------------
__global__ __launch_bounds__(256) void k_cast_w3(const float* __restrict__ w0,
                                                 const float* __restrict__ w1,
                                                 const float* __restrict__ w2,
                                                 _Float16* __restrict__ out, int n4each) {
  int i = blockIdx.x * 256 + threadIdx.x;
  if (i >= 3 * n4each) return;
  const float* src = (i < n4each) ? w0 : (i < 2 * n4each ? w1 : w2);
  int j = (i < n4each) ? i : (i < 2 * n4each ? i - n4each : i - 2 * n4each);
  f32x4 v = ((const f32x4*)src)[j];
  f16x4 o = { (_Float16)v.x, (_Float16)v.y, (_Float16)v.z, (_Float16)v.w };
  ((f16x4*)out)[i] = o;
}

// ---------------- 256x256 GEMM (KV projection), fp16 out -------------------
// All 4 half-tile stages of T+1 issued at T.P1. Gates: P1 vmcnt(8) (forces
// A1,B1 of T; 4 phases after issue), P4 vmcnt(4) (forces A0,B0 of T+1).
__global__ __launch_bounds__(512, 2) void k_gemm256(
    const _Float16* __restrict__ A, const _Float16* __restrict__ Bw,
    const float* __restrict__ biasA, const float* __restrict__ biasB, int nsplit,
    _Float16* __restrict__ C, int ldC, int nbn) {
  extern __shared__ char smem[];
  const int tid  = threadIdx.x;
  const int lane = tid & 63;
  const int wid  = tid >> 6;
  const int wr = wid >> 2, wc = wid & 3;

  const int nwg = gridDim.x;
  const int cpx = nwg >> 3;
  const int swz = (blockIdx.x & 7) * cpx + (blockIdx.x >> 3);
  const int bm = swz / nbn, bn = swz % nbn;

  auto regBase = [](int slot, int isB, int half) -> unsigned {
    return (unsigned)(((slot * 2 + isB) * 2 + half) * 16384);
  };
  const int r8    = lane >> 3;
  const int sslot = (lane & 7) ^ r8;
  const char* aT = (const char*)(A  + (size_t)bm * 256 * DIMN);
  const char* bT = (const char*)(Bw + (size_t)bn * 256 * DIMN);

  auto stage = [&](int isB, int half, int slot, int kt) {
    const char* gb = (isB ? bT : aT) + (size_t)(half * 128) * 2048 + kt * 128;
    const unsigned reg = regBase(slot, isB, half);
#pragma unroll
    for (int i = 0; i < 2; ++i) {
      const int c = wid * 2 + i;
      const char* src = gb + (size_t)(c * 8 + r8) * 2048 + (sslot << 4);
      __builtin_amdgcn_global_load_lds(
          (const __attribute__((address_space(1))) void*)src,
          (__attribute__((address_space(3))) void*)(smem + reg + c * 1024), 16, 0, 0);
    }
  };
  auto fragA = [&](int slot, int m, int kk) -> f16x8 {
    const int half = m >> 2;
    const int row  = wr * 64 + (m & 3) * 16 + (lane & 15);
    const int sl   = (kk * 4 + (lane >> 4)) ^ (row & 7);
    return *(const f16x8*)(smem + regBase(slot, 0, half) + row * 128 + (sl << 4));
  };
  auto fragB = [&](int slot, int n, int kk) -> f16x8 {
    const int half = n >> 1;
    const int row  = wc * 32 + (n & 1) * 16 + (lane & 15);
    const int sl   = (kk * 4 + (lane >> 4)) ^ (row & 7);
    return *(const f16x8*)(smem + regBase(slot, 1, half) + row * 128 + (sl << 4));
  };

  f32x4 acc[8][4];
#pragma unroll
  for (int m = 0; m < 8; ++m)
#pragma unroll
    for (int n = 0; n < 4; ++n) acc[m][n] = (f32x4){0.f, 0.f, 0.f, 0.f};

  // prologue: stage tile 0 into slot 0 (order A0,B0,A1,B1)
  stage(0, 0, 0, 0); stage(1, 0, 0, 0); stage(0, 1, 0, 0); stage(1, 1, 0, 0);
  asm volatile("s_waitcnt vmcnt(4)" ::: "memory");
  __builtin_amdgcn_s_barrier();

  f16x8 a[4][2], b0[2][2], b1[2][2];
#pragma unroll 2
  for (int T = 0; T < NT; ++T) {
    const int slot = T & 1, ns = slot ^ 1;
    const bool pf = (T + 1 < NT);
    // ---- P1 ----
    if (pf) {  // issue ALL of tile T+1's staging now (deep prefetch)
      stage(0, 0, ns, T + 1); stage(1, 0, ns, T + 1);
      stage(0, 1, ns, T + 1); stage(1, 1, ns, T + 1);
    }
#pragma unroll
    for (int m = 0; m < 4; ++m) { a[m][0] = fragA(slot, m, 0); a[m][1] = fragA(slot, m, 1); }
#pragma unroll
    for (int n = 0; n < 2; ++n) { b0[n][0] = fragB(slot, n, 0); b0[n][1] = fragB(slot, n, 1); }
    if (pf) asm volatile("s_waitcnt vmcnt(8)" ::: "memory");   // forces A1,B1 of T
    else    asm volatile("s_waitcnt vmcnt(0)" ::: "memory");
    __builtin_amdgcn_s_barrier();
    __builtin_amdgcn_s_setprio(1);
#pragma unroll
    for (int m = 0; m < 4; ++m)
#pragma unroll
      for (int n = 0; n < 2; ++n) {
        acc[m][n] = __builtin_amdgcn_mfma_f32_16x16x32_f16(a[m][0], b0[n][0], acc[m][n], 0, 0, 0);
        acc[m][n] = __builtin_amdgcn_mfma_f32_16x16x32_f16(a[m][1], b0[n][1], acc[m][n], 0, 0, 0);
      }
    __builtin_amdgcn_s_setprio(0);
    __builtin_amdgcn_s_barrier();
    // ---- P2 ----
#pragma unroll
    for (int n = 0; n < 2; ++n) { b1[n][0] = fragB(slot, n + 2, 0); b1[n][1] = fragB(slot, n + 2, 1); }
    __builtin_amdgcn_s_barrier();
    __builtin_amdgcn_s_setprio(1);
#pragma unroll
    for (int m = 0; m < 4; ++m)
#pragma unroll
      for (int n = 0; n < 2; ++n) {
        acc[m][n + 2] = __builtin_amdgcn_mfma_f32_16x16x32_f16(a[m][0], b1[n][0], acc[m][n + 2], 0, 0, 0);
        acc[m][n + 2] = __builtin_amdgcn_mfma_f32_16x16x32_f16(a[m][1], b1[n][1], acc[m][n + 2], 0, 0, 0);
      }
    __builtin_amdgcn_s_setprio(0);
    __builtin_amdgcn_s_barrier();
    // ---- P3 ----
#pragma unroll
    for (int m = 0; m < 4; ++m) { a[m][0] = fragA(slot, m + 4, 0); a[m][1] = fragA(slot, m + 4, 1); }
    __builtin_amdgcn_s_barrier();
    __builtin_amdgcn_s_setprio(1);
#pragma unroll
    for (int m = 0; m < 4; ++m)
#pragma unroll
      for (int n = 0; n < 2; ++n) {
        acc[m + 4][n] = __builtin_amdgcn_mfma_f32_16x16x32_f16(a[m][0], b0[n][0], acc[m + 4][n], 0, 0, 0);
        acc[m + 4][n] = __builtin_amdgcn_mfma_f32_16x16x32_f16(a[m][1], b0[n][1], acc[m + 4][n], 0, 0, 0);
      }
    __builtin_amdgcn_s_setprio(0);
    __builtin_amdgcn_s_barrier();
    // ---- P4 ----
    if (pf) asm volatile("s_waitcnt vmcnt(4)" ::: "memory");   // forces A0,B0 of T+1
    __builtin_amdgcn_s_barrier();
    __builtin_amdgcn_s_setprio(1);
#pragma unroll
    for (int m = 0; m < 4; ++m)
#pragma unroll
      for (int n = 0; n < 2; ++n) {
        acc[m + 4][n + 2] = __builtin_amdgcn_mfma_f32_16x16x32_f16(a[m][0], b1[n][0], acc[m + 4][n + 2], 0, 0, 0);
        acc[m + 4][n + 2] = __builtin_amdgcn_mfma_f32_16x16x32_f16(a[m][1], b1[n][1], acc[m + 4][n + 2], 0, 0, 0);
      }
    __builtin_amdgcn_s_setprio(0);
    __builtin_amdgcn_s_barrier();
  }

  const int r0 = bm * 256 + wr * 64 + ((lane >> 4) << 2);
  const int c0 = bn * 256 + wc * 32 + (lane & 15);
#pragma unroll
  for (int n = 0; n < 4; ++n) {
    const int col = c0 + (n >> 1) * 128 + (n & 1) * 16;
    const float bc = (col < nsplit) ? biasA[col] : biasB[col - nsplit];
#pragma unroll
    for (int m = 0; m < 8; ++m) {
      const int row = r0 + (m >> 2) * 128 + (m & 3) * 16;
#pragma unroll
      for (int t = 0; t < 4; ++t) {
        C[(size_t)(row + t) * ldC + col] = (_Float16)(acc[m][n][t] + bc);
      }
    }
  }
}

// ---------------- 128x256 GEMM (output projection), 3-slot deep pipeline ---
// LDS 144KB: slot s at s*49152 (A 16KB, B 32KB). Stage tile T+2 at T.P1.
// Single gate per tile at P2: vmcnt(6) forces ALL of stage(T+1).
__global__ __launch_bounds__(512, 2) void k_gemm_out(
    const _Float16* __restrict__ A, const _Float16* __restrict__ Bw,
    const float* __restrict__ bias, const _Float16* __restrict__ residH,
    float* __restrict__ C, int nbn) {
  extern __shared__ char smem[];
  const int tid  = threadIdx.x;
  const int lane = tid & 63;
  const int wid  = tid >> 6;
  const int wr = wid >> 2, wc = wid & 3;

  const int nwg = gridDim.x;
  const int cpx = nwg >> 3;
  const int swz = (blockIdx.x & 7) * cpx + (blockIdx.x >> 3);
  const int bm = swz / nbn, bn = swz % nbn;

  const int r8    = lane >> 3;
  const int sslot = (lane & 7) ^ r8;
  const char* aT = (const char*)(A  + (size_t)bm * 128 * DIMN);
  const char* bT = (const char*)(Bw + (size_t)bn * 256 * DIMN);

  auto stage3 = [&](int slot, int kt) {  // 6 loads: A(2), B(4)
    char* base = smem + slot * 49152;
#pragma unroll
    for (int i = 0; i < 2; ++i) {
      const int c = wid * 2 + i;                      // A: 16 chunks
      const char* src = aT + kt * 128 + (size_t)(c * 8 + r8) * 2048 + (sslot << 4);
      __builtin_amdgcn_global_load_lds(
          (const __attribute__((address_space(1))) void*)src,
          (__attribute__((address_space(3))) void*)(base + c * 1024), 16, 0, 0);
    }
#pragma unroll
    for (int i = 0; i < 4; ++i) {
      const int c = wid * 4 + i;                      // B: 32 chunks
      const char* src = bT + kt * 128 + (size_t)(c * 8 + r8) * 2048 + (sslot << 4);
      __builtin_amdgcn_global_load_lds(
          (const __attribute__((address_space(1))) void*)src,
          (__attribute__((address_space(3))) void*)(base + 16384 + c * 1024), 16, 0, 0);
    }
  };
  auto fragA = [&](int slot, int m, int kk) -> f16x8 {
    const int row = wr * 64 + m * 16 + (lane & 15);           // 0..127
    const int sl  = (kk * 4 + (lane >> 4)) ^ (row & 7);
    return *(const f16x8*)(smem + slot * 49152 + row * 128 + (sl << 4));
  };
  auto fragB = [&](int slot, int n, int kk) -> f16x8 {
    const int row = (n >> 1) * 128 + wc * 32 + (n & 1) * 16 + (lane & 15);  // 0..255
    const int sl  = (kk * 4 + (lane >> 4)) ^ (row & 7);
    return *(const f16x8*)(smem + slot * 49152 + 16384 + row * 128 + (sl << 4));
  };

  f32x4 acc[4][4];
#pragma unroll
  for (int m = 0; m < 4; ++m)
#pragma unroll
    for (int n = 0; n < 4; ++n) acc[m][n] = (f32x4){0.f, 0.f, 0.f, 0.f};

  // prologue: stage tiles 0 and 1; force tile 0 fully
  stage3(0, 0); stage3(1, 1);
  asm volatile("s_waitcnt vmcnt(6)" ::: "memory");
  __builtin_amdgcn_s_barrier();

  f16x8 a[4][2], b0[2][2], b1[2][2];
#pragma unroll 2
  for (int T = 0; T < NT; ++T) {
    const int s = T % 3, sw = (T + 2) % 3;
    // ---- P1 ----
    if (T + 2 < NT) stage3(sw, T + 2);
#pragma unroll
    for (int m = 0; m < 4; ++m) { a[m][0] = fragA(s, m, 0); a[m][1] = fragA(s, m, 1); }
#pragma unroll
    for (int n = 0; n < 2; ++n) { b0[n][0] = fragB(s, n, 0); b0[n][1] = fragB(s, n, 1); }
    __builtin_amdgcn_s_barrier();
    __builtin_amdgcn_s_setprio(1);
#pragma unroll
    for (int m = 0; m < 4; ++m)
#pragma unroll
      for (int n = 0; n < 2; ++n) {
        acc[m][n] = __builtin_amdgcn_mfma_f32_16x16x32_f16(a[m][0], b0[n][0], acc[m][n], 0, 0, 0);
        acc[m][n] = __builtin_amdgcn_mfma_f32_16x16x32_f16(a[m][1], b0[n][1], acc[m][n], 0, 0, 0);
      }
    __builtin_amdgcn_s_setprio(0);
    __builtin_amdgcn_s_barrier();
    // ---- P2 ----
#pragma unroll
    for (int n = 0; n < 2; ++n) { b1[n][0] = fragB(s, n + 2, 0); b1[n][1] = fragB(s, n + 2, 1); }
    if (T < NT - 2)       asm volatile("s_waitcnt vmcnt(6)" ::: "memory");  // forces stage(T+1)
    else if (T == NT - 2) asm volatile("s_waitcnt vmcnt(0)" ::: "memory");
    __builtin_amdgcn_s_barrier();
    __builtin_amdgcn_s_setprio(1);
#pragma unroll
    for (int m = 0; m < 4; ++m)
#pragma unroll
      for (int n = 0; n < 2; ++n) {
        acc[m][n + 2] = __builtin_amdgcn_mfma_f32_16x16x32_f16(a[m][0], b1[n][0], acc[m][n + 2], 0, 0, 0);
        acc[m][n + 2] = __builtin_amdgcn_mfma_f32_16x16x32_f16(a[m][1], b1[n][1], acc[m][n + 2], 0, 0, 0);
      }
    __builtin_amdgcn_s_setprio(0);
    __builtin_amdgcn_s_barrier();
  }

  const int r0 = bm * 128 + wr * 64 + ((lane >> 4) << 2);
  const int c0 = bn * 256 + wc * 32 + (lane & 15);
#pragma unroll
  for (int n = 0; n < 4; ++n) {
    const int col = c0 + (n >> 1) * 128 + (n & 1) * 16;
    const float bc = bias[col];
#pragma unroll
    for (int m = 0; m < 4; ++m) {
      const int row = r0 + m * 16;
#pragma unroll
      for (int t = 0; t < 4; ++t) {
        const size_t off = (size_t)(row + t) * DIMN + col;
        C[off] = acc[m][n][t] + bc + (float)residH[off];
      }
    }
  }
}

// ---------------- segment sums over fp16 KV (recompute normalize+bind) -----
__global__ __launch_bounds__(256) void k_segsum(const _Float16* __restrict__ KVh,
                                                float* __restrict__ segsum) {
  const int b = blockIdx.x >> 7, seg = blockIdx.x & 127, n = threadIdx.x;
  f32x4 ssum = (f32x4){0.f, 0.f, 0.f, 0.f};
  const size_t rb = (size_t)(b * LSEQ + seg * SL) * 2048 + n * 4;
  for (int l = 0; l < SL; ++l) {
    const size_t p = rb + (size_t)l * 2048;
    f32x4 kq = h2f(*(const f16x4*)(KVh + p));
    f32x4 vq = h2f(*(const f16x4*)(KVh + p + 1024));
    float nn = sqrtf(kq.x*kq.x + kq.y*kq.y + kq.z*kq.z + kq.w*kq.w);
    f32x4 kh = kq * (1.0f / fmaxf(nn, 1e-12f));
    ssum += qmul(vq, kh);
  }
  ((f32x4*)segsum)[(size_t)blockIdx.x * 256 + n] = ssum;
}

// ---------------- exclusive scan of segment sums ---------------------------
__global__ __launch_bounds__(256) void k_segscan(const float* __restrict__ segsum,
                                                 float* __restrict__ segoff) {
  const int gt = blockIdx.x * 256 + threadIdx.x;  // 0..4095
  const int b = gt >> 10, ch = gt & 1023;
  float run = 0.f;
  for (int s = 0; s < SEG; ++s) {
    const size_t idx = ((size_t)(b * SEG + s)) * 1024 + ch;
    float v = segsum[idx];
    segoff[idx] = run;
    run += v;
  }
}

// ---------------- retrieve + LayerNorm fused (fp16 KV, recompute bind) -----
__global__ __launch_bounds__(256) void k_retrieve_ln(
    const _Float16* __restrict__ KVh, const float* __restrict__ segoff,
    const float* __restrict__ g, const float* __restrict__ bb,
    _Float16* __restrict__ out) {
  const int b = blockIdx.x >> 7, seg = blockIdx.x & 127, n = threadIdx.x;
  const int wid = n >> 6, lane = n & 63;
  __shared__ float p1[2][4], p2[2][4];
  f32x4 mem = ((const f32x4*)segoff)[(size_t)blockIdx.x * 256 + n];
  const f32x4 gg  = ((const f32x4*)g)[n];
  const f32x4 bvv = ((const f32x4*)bb)[n];
  const size_t rb = (size_t)(b * LSEQ + seg * SL) * 2048 + n * 4;
  const int grow = b * LSEQ + seg * SL;

  f16x4 kq = *(const f16x4*)(KVh + rb);
  f16x4 vq = *(const f16x4*)(KVh + rb + 1024);
  for (int l = 0; l < SL; ++l) {
    f16x4 kqn, vqn;
    if (l + 1 < SL) {  // prefetch next row before the barrier
      kqn = *(const f16x4*)(KVh + rb + (size_t)(l + 1) * 2048);
      vqn = *(const f16x4*)(KVh + rb + (size_t)(l + 1) * 2048 + 1024);
    }
    f32x4 kf = h2f(kq), vf = h2f(vq);
    float nn = sqrtf(kf.x*kf.x + kf.y*kf.y + kf.z*kf.z + kf.w*kf.w);
    f32x4 kh = kf * (1.0f / fmaxf(nn, 1e-12f));
    mem += qmul(vf, kh);
    f32x4 kc = (f32x4){kh.x, -kh.y, -kh.z, -kh.w};
    f32x4 r = qmul(mem, kc);
    r *= rsqrtf((float)(seg * SL + l + 1));

    float s1 = r.x + r.y + r.z + r.w;
    float s2 = r.x*r.x + r.y*r.y + r.z*r.z + r.w*r.w;
#pragma unroll
    for (int off = 32; off > 0; off >>= 1) {
      s1 += __shfl_down(s1, off, 64);
      s2 += __shfl_down(s2, off, 64);
    }
    if (lane == 0) { p1[l & 1][wid] = s1; p2[l & 1][wid] = s2; }
    __syncthreads();
    const float ts1 = p1[l & 1][0] + p1[l & 1][1] + p1[l & 1][2] + p1[l & 1][3];
    const float ts2 = p2[l & 1][0] + p2[l & 1][1] + p2[l & 1][2] + p2[l & 1][3];
    const float mu = ts1 * (1.0f / 1024.0f);
    const float var = ts2 * (1.0f / 1024.0f) - mu * mu;
    const float rstd = rsqrtf(var + 1e-5f);
    f32x4 nv = (r - mu) * rstd * gg + bvv;
    f16x4 o = { (_Float16)nv.x, (_Float16)nv.y, (_Float16)nv.z, (_Float16)nv.w };
    ((f16x4*)out)[(size_t)(grow + l) * 256 + n] = o;
    kq = kqn; vq = vqn;
  }
}

// ---------------------------------------------------------------------------
extern "C" void kernel_launch(void* const* d_in, const int* in_sizes, int n_in,
                              void* d_out, int out_size, void* d_ws, size_t ws_size,
                              hipStream_t stream) {
  const float* x    = (const float*)d_in[0];
  const float* Wk   = (const float*)d_in[1];
  const float* bk   = (const float*)d_in[2];
  const float* Wv   = (const float*)d_in[3];
  const float* bv   = (const float*)d_in[4];
  const float* ln_g = (const float*)d_in[5];
  const float* ln_b = (const float*)d_in[6];
  const float* Wo   = (const float*)d_in[7];
  const float* bo   = (const float*)d_in[8];
  float* out = (float*)d_out;

  char* ws = (char*)d_ws;
  size_t off = 0;
  auto alloc = [&](size_t bytes) -> void* {
    void* p = ws + off;
    off += (bytes + 255) & ~(size_t)255;
    return p;
  };
  _Float16* xb   = (_Float16*)alloc((size_t)MROW * DIMN * 2);       // 33.5 MB
  _Float16* wkvb = (_Float16*)alloc((size_t)3 * DIMN * DIMN * 2);   // 6 MB (Wk||Wv||Wo)
  _Float16* KVh  = (_Float16*)alloc((size_t)MROW * 2 * DIMN * 2);   // 67 MB fp16 K|V
  float* segsum  = (float*)alloc((size_t)BATCH * SEG * DIMN * 4);   // 2 MB
  float* segoff  = (float*)alloc((size_t)BATCH * SEG * DIMN * 4);   // 2 MB
  _Float16* nb   = (_Float16*)alloc((size_t)MROW * DIMN * 2);       // 33.5 MB
  _Float16* wob  = wkvb + (size_t)2 * DIMN * DIMN;
  (void)off; (void)ws_size; (void)in_sizes; (void)n_in; (void)out_size;

  hipFuncSetAttribute((const void*)k_gemm256,
                      hipFuncAttributeMaxDynamicSharedMemorySize, 131072);
  hipFuncSetAttribute((const void*)k_gemm_out,
                      hipFuncAttributeMaxDynamicSharedMemorySize, 147456);

  // casts
  k_cast_f16<<<MROW * DIMN / 4 / 256, 256, 0, stream>>>(x, xb, MROW * DIMN / 4);
  k_cast_w3<<<3 * DIMN * DIMN / 4 / 256, 256, 0, stream>>>(Wk, Wv, Wo, wkvb, DIMN * DIMN / 4);

  // fused K|V projection: [16384][2048] fp16 = xb @ (Wk||Wv)^T
  k_gemm256<<<(MROW / 256) * (2048 / 256), 512, 131072, stream>>>(
      xb, wkvb, bk, bv, 1024, KVh, 2048, 2048 / 256);

  // segment sums (recompute bind) -> scan -> retrieve+LN
  k_segsum<<<BATCH * SEG, 256, 0, stream>>>(KVh, segsum);
  k_segscan<<<BATCH * DIMN / 256, 256, 0, stream>>>(segsum, segoff);
  k_retrieve_ln<<<BATCH * SEG, 256, 0, stream>>>(KVh, segoff, ln_g, ln_b, nb);

  // output GEMM with residual from xb
  k_gemm_out<<<(MROW / 128) * (DIMN / 256), 512, 147456, stream>>>(
      nb, wob, bo, xb, out, DIMN / 256);
}